// Round 1
// baseline (263.292 us; speedup 1.0000x reference)
//
#include <hip/hip_runtime.h>
#include <hip/hip_bf16.h>

#define N 8192
#define Dd 128

typedef short short8 __attribute__((ext_vector_type(8)));
typedef float floatx4 __attribute__((ext_vector_type(4)));

// round-to-nearest-even fp32 -> bf16 (no NaN in inputs)
static __device__ inline unsigned short f2bf(float f) {
    unsigned int u = __float_as_uint(f);
    unsigned int r = (u + 0x7fffu + ((u >> 16) & 1u)) >> 16;
    return (unsigned short)r;
}
static __device__ inline float bf2f(unsigned short b) {
    return __uint_as_float(((unsigned int)b) << 16);
}

// One wave per row: convert to bf16, store, and compute row norm of the
// *rounded* values so the gram diagonal cancels exactly.
__global__ __launch_bounds__(256) void prep_kernel(const float* __restrict__ z,
                                                   unsigned short* __restrict__ zb,
                                                   float* __restrict__ sq) {
    int row  = blockIdx.x * 4 + (threadIdx.x >> 6);
    int lane = threadIdx.x & 63;
    float2 v = ((const float2*)z)[row * 64 + lane];
    unsigned short b0 = f2bf(v.x);
    unsigned short b1 = f2bf(v.y);
    float f0 = bf2f(b0), f1 = bf2f(b1);
    ushort2 st; st.x = b0; st.y = b1;
    ((ushort2*)zb)[row * 64 + lane] = st;
    float s = f0 * f0 + f1 * f1;
    #pragma unroll
    for (int off = 32; off > 0; off >>= 1) s += __shfl_down(s, off, 64);
    if (lane == 0) sq[row] = s;
}

// 128x128 output tile per block; whole K=128 staged once into LDS.
// LDS layout: row-major [128][128] bf16, with 16B chunks XOR-swizzled by
// (row & 15) so both staging ds_write_b128 and fragment ds_read_b128 spread
// evenly over banks (8 lanes per 4-bank group = conflict-free wave access).
__global__ __launch_bounds__(256, 2) void pairsim_kernel(const unsigned short* __restrict__ zb,
                                                         const float* __restrict__ sq,
                                                         float* __restrict__ out) {
    __shared__ unsigned short lA[128 * 128];
    __shared__ unsigned short lB[128 * 128];

    int bx = blockIdx.x, by = blockIdx.y;
    int colBase = bx * 128, rowBase = by * 128;
    int t  = threadIdx.x;
    int r0 = t >> 4, cg = t & 15;   // 16 rows x 16 chunks per pass, 8 passes

    const uint4* gA = (const uint4*)(zb + (size_t)rowBase * Dd);
    const uint4* gB = (const uint4*)(zb + (size_t)colBase * Dd);
    uint4 va[8], vb[8];
    #pragma unroll
    for (int i = 0; i < 8; i++) va[i] = gA[(r0 + i * 16) * 16 + cg];
    #pragma unroll
    for (int i = 0; i < 8; i++) vb[i] = gB[(r0 + i * 16) * 16 + cg];

    int scg = ((cg ^ r0) * 8);      // swizzled chunk offset (elements)
    #pragma unroll
    for (int i = 0; i < 8; i++) *(uint4*)&lA[(r0 + i * 16) * 128 + scg] = va[i];
    #pragma unroll
    for (int i = 0; i < 8; i++) *(uint4*)&lB[(r0 + i * 16) * 128 + scg] = vb[i];
    __syncthreads();

    int w = t >> 6, lane = t & 63;
    int wr = (w >> 1) * 64, wc = (w & 1) * 64;   // 2x2 waves -> 64x64 each
    int m = lane & 15, quad = lane >> 4;

    floatx4 zero = {0.f, 0.f, 0.f, 0.f};
    floatx4 acc[4][4];
    #pragma unroll
    for (int i = 0; i < 4; i++)
        #pragma unroll
        for (int j = 0; j < 4; j++) acc[i][j] = zero;

    #pragma unroll
    for (int ks = 0; ks < 4; ks++) {
        short8 af[4], bfr[4];
        int c = ks * 4 + quad;      // 16B chunk index along K
        #pragma unroll
        for (int i = 0; i < 4; i++)
            af[i] = *(const short8*)&lA[(wr + i * 16 + m) * 128 + ((c ^ m) * 8)];
        #pragma unroll
        for (int j = 0; j < 4; j++)
            bfr[j] = *(const short8*)&lB[(wc + j * 16 + m) * 128 + ((c ^ m) * 8)];
        #pragma unroll
        for (int i = 0; i < 4; i++)
            #pragma unroll
            for (int j = 0; j < 4; j++)
                acc[i][j] = __builtin_amdgcn_mfma_f32_16x16x32_bf16(af[i], bfr[j], acc[i][j], 0, 0, 0);
    }

    // Epilogue: exp(-max(sq_r + sq_c - 2g, 0)) fused, fp32 store.
    // C/D layout (m89-verified): col = lane&15, row = quad*4 + reg.
    #pragma unroll
    for (int j = 0; j < 4; j++) {
        int col = colBase + wc + j * 16 + m;
        float sc = sq[col];
        #pragma unroll
        for (int i = 0; i < 4; i++) {
            #pragma unroll
            for (int r = 0; r < 4; r++) {
                int row = rowBase + wr + i * 16 + quad * 4 + r;
                float sr = sq[row];
                float g = acc[i][j][r];
                float e = fminf(2.0f * g - sr - sc, 0.0f);
                out[(size_t)row * N + col] = __expf(e);
            }
        }
    }
}

extern "C" void kernel_launch(void* const* d_in, const int* in_sizes, int n_in,
                              void* d_out, int out_size, void* d_ws, size_t ws_size,
                              hipStream_t stream) {
    const float* z = (const float*)d_in[0];
    unsigned short* zb = (unsigned short*)d_ws;                       // 2 MB bf16 copy
    float* sqv = (float*)((char*)d_ws + (size_t)N * Dd * sizeof(unsigned short)); // 32 KB norms
    float* out = (float*)d_out;

    prep_kernel<<<N / 4, 256, 0, stream>>>(z, zb, sqv);
    pairsim_kernel<<<dim3(64, 64), 256, 0, stream>>>(zb, sqv, out);
}